// Round 1
// baseline (522.214 us; speedup 1.0000x reference)
//
#include <hip/hip_runtime.h>
#include <hip/hip_bf16.h>
#include <stdint.h>

// VectorQuantization: out[n] = codebook[argmax_k dot(x[n], codebook[k])]
// (L2-normalize is a positive row-scalar -> argmax-invariant -> skipped)
//
// Pipeline:
//  1) split_hi_lo: fp32 -> (bf16 hi, bf16 lo) for x and codebook (in d_ws)
//  2) vq_argmax: 128x128-tile MFMA GEMM (3 passes hi*hi + hi*lo + lo*hi ->
//     fp32-accurate sims) with fused per-row argmax epilogue; partials to ws
//  3) reduce_gather: reduce NSPLIT partials per row, gather codebook row (exact fp32 copy)

typedef __bf16 bf16x8 __attribute__((ext_vector_type(8)));
typedef float f32x4 __attribute__((ext_vector_type(4)));

#define M_ROWS 8192
#define DIM 512
#define K_CODES 16384
#define BM 128
#define BN 128
#define BK 32
#define NSPLIT 16
#define NTILES ((K_CODES / NSPLIT) / BN) /* 8 */
#define NEG_INF (-3.402823466e+38f)

typedef __attribute__((address_space(1))) uint32_t as1_u32;
typedef __attribute__((address_space(3))) uint32_t as3_u32;

__device__ __forceinline__ void gll16(const void* g, void* l) {
  // async global->LDS, 16B/lane; LDS dest = wave-uniform base + lane*16
  __builtin_amdgcn_global_load_lds((const as1_u32*)(uintptr_t)g,
                                   (as3_u32*)(uintptr_t)l, 16, 0, 0);
}

// stage a [128 rows x 32 cols] bf16 tile (8 KB) from row-major [*, DIM] source.
// g_base points at [tile_row0][k0]. 2 rounds x 256 threads x 16B.
__device__ __forceinline__ void stage_tile(const __bf16* __restrict__ g_base,
                                           __bf16* lds_tile, int tid) {
#pragma unroll
  for (int r = 0; r < 2; ++r) {
    const int lin = r * 256 + tid;      // 0..511 -> 16B chunk id
    const int row = lin >> 2;           // 4 chunks per 64B row
    const int col = (lin & 3) << 3;     // element col (8 bf16 = 16B)
    const __bf16* g = g_base + (size_t)row * DIM + col;
    // wave-uniform LDS base: chunk id of this wave's lane 0, in elements
    __bf16* l = lds_tile + ((size_t)(r * 256 + (tid & 192)) << 3);
    gll16((const void*)g, (void*)l);
  }
}

__global__ void split_hi_lo(const float* __restrict__ src, __bf16* __restrict__ hi,
                            __bf16* __restrict__ lo, int n4) {
  int i = blockIdx.x * 256 + threadIdx.x;
  if (i >= n4) return;
  const float4 v = reinterpret_cast<const float4*>(src)[i];
  float f[4] = {v.x, v.y, v.z, v.w};
  unsigned short hb[4], lb[4];
#pragma unroll
  for (int j = 0; j < 4; ++j) {
    __bf16 h = (__bf16)f[j];
    __bf16 l = (__bf16)(f[j] - (float)h);
    hb[j] = __builtin_bit_cast(unsigned short, h);
    lb[j] = __builtin_bit_cast(unsigned short, l);
  }
  reinterpret_cast<ushort4*>(hi)[i] = make_ushort4(hb[0], hb[1], hb[2], hb[3]);
  reinterpret_cast<ushort4*>(lo)[i] = make_ushort4(lb[0], lb[1], lb[2], lb[3]);
}

__global__ __launch_bounds__(256, 2) void vq_argmax(
    const __bf16* __restrict__ xh, const __bf16* __restrict__ xl,
    const __bf16* __restrict__ ch, const __bf16* __restrict__ cl,
    float* __restrict__ part_v, int* __restrict__ part_i) {
  __shared__ __bf16 sxh[BM * BK];
  __shared__ __bf16 sxl[BM * BK];
  __shared__ __bf16 sch[BN * BK];
  __shared__ __bf16 scl[BN * BK];
  __shared__ float red_v[2][BM];
  __shared__ int red_i[2][BM];

  const int tid = threadIdx.x;
  const int w = tid >> 6, lane = tid & 63;
  const int wm = w & 1, wn = w >> 1;        // 2x2 wave grid over 128x128 tile
  const int l15 = lane & 15, quad = lane >> 4;
  const int row0 = blockIdx.x * BM;
  const int split = blockIdx.y;
  const int n_split = split * (K_CODES / NSPLIT);

  float bv[4][4];
  int bi[4][4];
#pragma unroll
  for (int i = 0; i < 4; ++i)
#pragma unroll
    for (int r = 0; r < 4; ++r) {
      bv[i][r] = NEG_INF;
      bi[i][r] = 0x7fffffff;
    }

#pragma unroll 1
  for (int nt = 0; nt < NTILES; ++nt) {
    const int n0 = n_split + nt * BN;
    f32x4 acc[4][4];
#pragma unroll
    for (int i = 0; i < 4; ++i)
#pragma unroll
      for (int j = 0; j < 4; ++j) acc[i][j] = (f32x4){0.f, 0.f, 0.f, 0.f};

#pragma unroll 1
    for (int ks = 0; ks < DIM / BK; ++ks) {
      const int k0 = ks * BK;
      stage_tile(xh + (size_t)row0 * DIM + k0, sxh, tid);
      stage_tile(xl + (size_t)row0 * DIM + k0, sxl, tid);
      stage_tile(ch + (size_t)n0 * DIM + k0, sch, tid);
      stage_tile(cl + (size_t)n0 * DIM + k0, scl, tid);
      __syncthreads();  // compiler drains vmcnt before s_barrier

      bf16x8 Ah[4], Al[4], Bh[4], Bl[4];
#pragma unroll
      for (int i = 0; i < 4; ++i) {
        // A frag: m = lane&15, k = quad*8 + j (8 contiguous bf16 = one b128)
        Ah[i] = *(const bf16x8*)&sxh[(wm * 64 + i * 16 + l15) * BK + quad * 8];
        Al[i] = *(const bf16x8*)&sxl[(wm * 64 + i * 16 + l15) * BK + quad * 8];
        Bh[i] = *(const bf16x8*)&sch[(wn * 64 + i * 16 + l15) * BK + quad * 8];
        Bl[i] = *(const bf16x8*)&scl[(wn * 64 + i * 16 + l15) * BK + quad * 8];
      }
#pragma unroll
      for (int i = 0; i < 4; ++i)
#pragma unroll
        for (int j = 0; j < 4; ++j) {
          acc[i][j] = __builtin_amdgcn_mfma_f32_16x16x32_bf16(Ah[i], Bh[j], acc[i][j], 0, 0, 0);
          acc[i][j] = __builtin_amdgcn_mfma_f32_16x16x32_bf16(Ah[i], Bl[j], acc[i][j], 0, 0, 0);
          acc[i][j] = __builtin_amdgcn_mfma_f32_16x16x32_bf16(Al[i], Bh[j], acc[i][j], 0, 0, 0);
        }
      __syncthreads();
    }

    // fused argmax epilogue over this 128-col tile
    // C/D layout: row = i*16 + quad*4 + reg, col = j*16 + (lane&15)
#pragma unroll
    for (int i = 0; i < 4; ++i)
#pragma unroll
      for (int r = 0; r < 4; ++r) {
        float v = NEG_INF;
        int ci = 0x7fffffff;
#pragma unroll
        for (int j = 0; j < 4; ++j) {
          float s = acc[i][j][r];
          int c = n0 + wn * 64 + j * 16 + l15;
          if (s > v) { v = s; ci = c; }  // strict > keeps lowest col on tie
        }
        // butterfly across the 16 lanes of this quad (cols)
#pragma unroll
        for (int d = 1; d < 16; d <<= 1) {
          float ov = __shfl_xor(v, d);
          int oi = __shfl_xor(ci, d);
          if (ov > v || (ov == v && oi < ci)) { v = ov; ci = oi; }
        }
        if (v > bv[i][r] || (v == bv[i][r] && ci < bi[i][r])) {
          bv[i][r] = v;
          bi[i][r] = ci;
        }
      }
  }

  // combine the two column-halves (wn=0,1) per row, write per-block partial
  if (l15 == 0) {
#pragma unroll
    for (int i = 0; i < 4; ++i)
#pragma unroll
      for (int r = 0; r < 4; ++r) {
        const int rl = wm * 64 + i * 16 + quad * 4 + r;
        red_v[wn][rl] = bv[i][r];
        red_i[wn][rl] = bi[i][r];
      }
  }
  __syncthreads();
  if (tid < BM) {
    float v0 = red_v[0][tid], v1 = red_v[1][tid];
    int i0 = red_i[0][tid], i1 = red_i[1][tid];
    bool take1 = (v1 > v0) || (v1 == v0 && i1 < i0);
    const size_t o = (size_t)(row0 + tid) * NSPLIT + split;
    part_v[o] = take1 ? v1 : v0;
    part_i[o] = take1 ? i1 : i0;
  }
}

__global__ void reduce_gather(const float* __restrict__ part_v, const int* __restrict__ part_i,
                              const float* __restrict__ cb, float* __restrict__ out) {
  const int row = blockIdx.x;
  const int lane = threadIdx.x;
  float v = NEG_INF;
  int ci = 0x7fffffff;
  if (lane < NSPLIT) {
    v = part_v[(size_t)row * NSPLIT + lane];
    ci = part_i[(size_t)row * NSPLIT + lane];
  }
#pragma unroll
  for (int d = 1; d < NSPLIT; d <<= 1) {
    float ov = __shfl_xor(v, d);
    int oi = __shfl_xor(ci, d);
    if (ov > v || (ov == v && oi < ci)) { v = ov; ci = oi; }
  }
  const int best = __shfl(ci, 0);
  const float4* src = (const float4*)(cb + (size_t)best * DIM);
  float4* dst = (float4*)(out + (size_t)row * DIM);
  dst[lane] = src[lane];        // 512 f32 = 128 float4, 64 lanes x 2
  dst[lane + 64] = src[lane + 64];
}

extern "C" void kernel_launch(void* const* d_in, const int* in_sizes, int n_in,
                              void* d_out, int out_size, void* d_ws, size_t ws_size,
                              hipStream_t stream) {
  const float* x = (const float*)d_in[0];
  const float* cb = (const float*)d_in[1];
  float* out = (float*)d_out;

  // ws layout: x_hi(8MB) x_lo(8MB) c_hi(16MB) c_lo(16MB) part_v(512KB) part_i(512KB)
  __bf16* xh = (__bf16*)d_ws;
  __bf16* xl = xh + (size_t)M_ROWS * DIM;
  __bf16* ch = xl + (size_t)M_ROWS * DIM;
  __bf16* cl = ch + (size_t)K_CODES * DIM;
  float* part_v = (float*)(cl + (size_t)K_CODES * DIM);
  int* part_i = (int*)(part_v + (size_t)M_ROWS * NSPLIT);

  split_hi_lo<<<(M_ROWS * DIM / 4) / 256, 256, 0, stream>>>(x, xh, xl, M_ROWS * DIM / 4);
  split_hi_lo<<<(K_CODES * DIM / 4) / 256, 256, 0, stream>>>(cb, ch, cl, K_CODES * DIM / 4);
  vq_argmax<<<dim3(M_ROWS / BM, NSPLIT), 256, 0, stream>>>(xh, xl, ch, cl, part_v, part_i);
  reduce_gather<<<M_ROWS, 64, 0, stream>>>(part_v, part_i, cb, out);
}